// Round 1
// baseline (558.822 us; speedup 1.0000x reference)
//
#include <hip/hip_runtime.h>

// SSD MultiBox loss, MI355X. B=32 batches, A=24564 anchors, C=81 classes, M=20 targets.
// Outputs: out[0]=class_loss, out[1]=loc_loss/N, out[2]=N  (fp32)

#define B_ 32
#define A_ 24564
#define C_ 81
#define M_ 20

constexpr float THRESH = 0.5f;
constexpr float VAR0 = 0.1f;
constexpr float VAR1 = 0.2f;
constexpr int GRIDX = (A_ + 63) / 64;     // 384 blocks in x, 64 anchors/block
constexpr int NBLK = GRIDX * B_;          // 12288 main blocks

// ---------------- K1: best anchor per (b, m) --------------------------------
// numpy argmax ties -> smallest index: pack (iou_bits, ~a) and take max.
__global__ __launch_bounds__(256) void k_best_anchor(
    const float* __restrict__ anchors, const float* __restrict__ targets,
    int* __restrict__ bestA) {
  int bm = blockIdx.x;                 // b*M + m
  const float* t = targets + (size_t)bm * 5;
  float tx0 = t[0], ty0 = t[1], tx1 = t[2], ty1 = t[3];
  float areaT = (tx1 - tx0) * (ty1 - ty0);
  unsigned long long best = 0ull;
  for (int a = threadIdx.x; a < A_; a += 256) {
    float4 an = ((const float4*)anchors)[a];
    float ax0 = an.x - an.z * 0.5f, ay0 = an.y - an.w * 0.5f;
    float ax1 = an.x + an.z * 0.5f, ay1 = an.y + an.w * 0.5f;
    float lx = fmaxf(tx0, ax0), ly = fmaxf(ty0, ay0);
    float rx = fminf(tx1, ax1), ry = fminf(ty1, ay1);
    float w = fmaxf(rx - lx, 0.0f), h = fmaxf(ry - ly, 0.0f);
    float inter = w * h;
    float iou = inter / (areaT + (ax1 - ax0) * (ay1 - ay0) - inter);
    unsigned long long key =
        ((unsigned long long)__float_as_uint(iou) << 32) |
        (unsigned long long)(0xFFFFFFFFu - (unsigned)a);
    best = (key > best) ? key : best;
  }
  __shared__ unsigned long long sh[256];
  sh[threadIdx.x] = best;
  __syncthreads();
  for (int s = 128; s > 0; s >>= 1) {
    if (threadIdx.x < s) {
      unsigned long long o = sh[threadIdx.x + s];
      if (o > sh[threadIdx.x]) sh[threadIdx.x] = o;
    }
    __syncthreads();
  }
  if (threadIdx.x == 0)
    bestA[bm] = (int)(0xFFFFFFFFu - (unsigned)(sh[0] & 0xFFFFFFFFull));
}

// ---------------- K2: match + CE + smooth-L1, 4 threads per anchor ----------
__global__ __launch_bounds__(256) void k_main(
    const float* __restrict__ pred_conf, const float* __restrict__ pred_loc,
    const float* __restrict__ anchors, const float* __restrict__ targets,
    const int* __restrict__ bestA, float* __restrict__ neg_ce,
    float* __restrict__ partLoc, float* __restrict__ partCe,
    int* __restrict__ posCount) {
  __shared__ float sT[M_ * 5];
  __shared__ int sBA[M_];
  int b = blockIdx.y;
  if (threadIdx.x < M_ * 5) sT[threadIdx.x] = targets[(size_t)b * M_ * 5 + threadIdx.x];
  if (threadIdx.x < M_) sBA[threadIdx.x] = bestA[b * M_ + threadIdx.x];
  __syncthreads();

  int g = threadIdx.x & 3;                 // class-split lane within group of 4
  int q = threadIdx.x >> 2;                // anchor slot within block
  int a = blockIdx.x * 64 + q;
  bool active = (a < A_);

  float myCe = 0.0f, myLoc = 0.0f;
  int myPos = 0;

  if (active) {
    float4 an = ((const float4*)anchors)[a];
    float ax0 = an.x - an.z * 0.5f, ay0 = an.y - an.w * 0.5f;
    float ax1 = an.x + an.z * 0.5f, ay1 = an.y + an.w * 0.5f;
    float areaA = (ax1 - ax0) * (ay1 - ay0);

    // argmax over M targets (first-max wins via strict >)
    float bestIou = -1.0f; int bestM = 0;
    #pragma unroll
    for (int m = 0; m < M_; ++m) {
      float tx0 = sT[m * 5 + 0], ty0 = sT[m * 5 + 1];
      float tx1 = sT[m * 5 + 2], ty1 = sT[m * 5 + 3];
      float lx = fmaxf(tx0, ax0), ly = fmaxf(ty0, ay0);
      float rx = fminf(tx1, ax1), ry = fminf(ty1, ay1);
      float w = fmaxf(rx - lx, 0.0f), h = fmaxf(ry - ly, 0.0f);
      float inter = w * h;
      float areaT = (tx1 - tx0) * (ty1 - ty0);
      float iou = inter / (areaT + areaA - inter);
      if (iou > bestIou) { bestIou = iou; bestM = m; }
    }
    // guarantee override, ascending m => last-m-wins (numpy scatter semantics)
    #pragma unroll
    for (int m = 0; m < M_; ++m)
      if (sBA[m] == a) { bestIou = 2.0f; bestM = m; }

    bool pos = (bestIou >= THRESH);
    int c = pos ? ((int)sT[bestM * 5 + 4] + 1) : 0;   // class index in [0,80]

    // log-sum-exp over 81 classes split across 4 lanes (static reg indexing)
    const float* row = pred_conf + ((size_t)b * A_ + a) * C_;
    float x[20];
    #pragma unroll
    for (int k = 0; k < 20; ++k) x[k] = row[g + 4 * k];
    float r80 = row[80];
    float v80 = (g == 0) ? r80 : -1e30f;

    float xm = v80;
    #pragma unroll
    for (int k = 0; k < 20; ++k) xm = fmaxf(xm, x[k]);
    xm = fmaxf(xm, __shfl_xor(xm, 1, 64));
    xm = fmaxf(xm, __shfl_xor(xm, 2, 64));

    float s = __expf(v80 - xm);
    #pragma unroll
    for (int k = 0; k < 20; ++k) s += __expf(x[k] - xm);
    s += __shfl_xor(s, 1, 64);
    s += __shfl_xor(s, 2, 64);

    float xc = 0.0f;
    #pragma unroll
    for (int k = 0; k < 20; ++k)
      if (g + 4 * k == c) xc = x[k];
    if (c == 80) xc = (g == 0) ? r80 : 0.0f;
    xc += __shfl_xor(xc, 1, 64);
    xc += __shfl_xor(xc, 2, 64);

    float ce = xm + __logf(s) - xc;

    if (g == 0) {
      neg_ce[(size_t)b * A_ + a] = pos ? -1.0f : ce;
      if (pos) {
        myPos = 1;
        myCe = ce;
        float4 pl = ((const float4*)pred_loc)[(size_t)b * A_ + a];
        float mx0 = sT[bestM * 5 + 0], my0 = sT[bestM * 5 + 1];
        float mx1 = sT[bestM * 5 + 2], my1 = sT[bestM * 5 + 3];
        float gcx = ((mx0 + mx1) * 0.5f - an.x) / (VAR0 * an.z);
        float gcy = ((my0 + my1) * 0.5f - an.y) / (VAR0 * an.w);
        float gw  = __logf((mx1 - mx0) / an.z) / VAR1;
        float gh  = __logf((my1 - my0) / an.w) / VAR1;
        float d0 = fabsf(pl.x - gcx), d1 = fabsf(pl.y - gcy);
        float d2 = fabsf(pl.z - gw),  d3 = fabsf(pl.w - gh);
        float s0 = d0 < 1.0f ? 0.5f * d0 * d0 : d0 - 0.5f;
        float s1 = d1 < 1.0f ? 0.5f * d1 * d1 : d1 - 0.5f;
        float s2 = d2 < 1.0f ? 0.5f * d2 * d2 : d2 - 0.5f;
        float s3 = d3 < 1.0f ? 0.5f * d3 * d3 : d3 - 0.5f;
        myLoc = s0 + s1 + s2 + s3;
      }
    }
  }

  // block reduce (wave shfl + LDS across 4 waves); partials avoid float atomics
  float rc = myCe, rl = myLoc; int rp = myPos;
  #pragma unroll
  for (int off = 32; off > 0; off >>= 1) {
    rc += __shfl_down(rc, off, 64);
    rl += __shfl_down(rl, off, 64);
    rp += __shfl_down(rp, off, 64);
  }
  __shared__ float swc[4], swl[4];
  __shared__ int swp[4];
  int w = threadIdx.x >> 6;
  if ((threadIdx.x & 63) == 0) { swc[w] = rc; swl[w] = rl; swp[w] = rp; }
  __syncthreads();
  if (threadIdx.x == 0) {
    float tc = swc[0] + swc[1] + swc[2] + swc[3];
    float tl = swl[0] + swl[1] + swl[2] + swl[3];
    int tp = swp[0] + swp[1] + swp[2] + swp[3];
    int pb = blockIdx.y * gridDim.x + blockIdx.x;
    partCe[pb] = tc;
    partLoc[pb] = tl;
    if (tp) atomicAdd(&posCount[b], tp);
  }
}

// ---------------- K3: per-batch exact top-K sum via MSB radix select --------
__global__ __launch_bounds__(256) void k_select(
    const float* __restrict__ neg_ce, const int* __restrict__ posCount,
    float* __restrict__ negSumB) {
  int b = blockIdx.x;
  const float* v = neg_ce + (size_t)b * A_;
  int p = posCount[b];
  int cand = A_ - p;
  int K = max(10, min(p * 3, A_ - p));
  if (K > cand) K = cand;
  if (K <= 0) { if (threadIdx.x == 0) negSumB[b] = 0.0f; return; }

  __shared__ int hist[256];
  __shared__ int shK;
  __shared__ unsigned shPrefix;
  unsigned prefix = 0;
  int Krem = K;

  for (int shift = 24; shift >= 0; shift -= 8) {
    hist[threadIdx.x] = 0;
    __syncthreads();
    for (int i = threadIdx.x; i < A_; i += 256) {
      float f = v[i];
      if (f >= 0.0f) {                         // positives marked -1.0f; ce >= 0
        unsigned u = __float_as_uint(f);
        bool match = (shift == 24) || ((u >> (shift + 8)) == prefix);
        if (match) atomicAdd(&hist[(u >> shift) & 0xFF], 1);
      }
    }
    __syncthreads();
    if (threadIdx.x == 0) {
      int cum = 0, digit = 0, kn = Krem;
      for (int t2 = 255; t2 >= 0; --t2) {
        if (cum + hist[t2] >= Krem) { digit = t2; kn = Krem - cum; break; }
        cum += hist[t2];
      }
      shPrefix = (prefix << 8) | (unsigned)digit;
      shK = kn;
    }
    __syncthreads();
    prefix = shPrefix;
    Krem = shK;
    __syncthreads();
  }

  float vk = __uint_as_float(prefix);          // K-th largest value (exact bits)
  double sum = 0.0; int cnt = 0;
  for (int i = threadIdx.x; i < A_; i += 256) {
    float f = v[i];
    if (f > vk) { sum += (double)f; cnt++; }   // vk >= 0 so sentinel excluded
  }
  #pragma unroll
  for (int off = 32; off > 0; off >>= 1) {
    sum += __shfl_down(sum, off, 64);
    cnt += __shfl_down(cnt, off, 64);
  }
  __shared__ double ssum[4];
  __shared__ int scnt[4];
  if ((threadIdx.x & 63) == 0) { ssum[threadIdx.x >> 6] = sum; scnt[threadIdx.x >> 6] = cnt; }
  __syncthreads();
  if (threadIdx.x == 0) {
    double tot = ssum[0] + ssum[1] + ssum[2] + ssum[3];
    int c2 = scnt[0] + scnt[1] + scnt[2] + scnt[3];
    negSumB[b] = (float)(tot + (double)(K - c2) * (double)vk);
  }
}

// ---------------- K4: finalize ---------------------------------------------
__global__ __launch_bounds__(256) void k_final(
    const int* __restrict__ posCount, const float* __restrict__ partLoc,
    const float* __restrict__ partCe, const float* __restrict__ negSumB,
    float* __restrict__ out) {
  double locS = 0.0, ceS = 0.0, negS = 0.0;
  int N = 0;
  for (int i = threadIdx.x; i < NBLK; i += 256) {
    locS += (double)partLoc[i];
    ceS  += (double)partCe[i];
  }
  if (threadIdx.x < B_) {
    N = posCount[threadIdx.x];
    negS = (double)negSumB[threadIdx.x];
  }
  #pragma unroll
  for (int off = 32; off > 0; off >>= 1) {
    locS += __shfl_down(locS, off, 64);
    ceS  += __shfl_down(ceS, off, 64);
    negS += __shfl_down(negS, off, 64);
    N    += __shfl_down(N, off, 64);
  }
  __shared__ double sL[4], sC[4], sG[4];
  __shared__ int sN[4];
  int w = threadIdx.x >> 6;
  if ((threadIdx.x & 63) == 0) { sL[w] = locS; sC[w] = ceS; sG[w] = negS; sN[w] = N; }
  __syncthreads();
  if (threadIdx.x == 0) {
    double L = sL[0] + sL[1] + sL[2] + sL[3];
    double Cc = sC[0] + sC[1] + sC[2] + sC[3];
    double G = sG[0] + sG[1] + sG[2] + sG[3];
    int n = sN[0] + sN[1] + sN[2] + sN[3];
    float fn = (float)n;
    out[0] = (float)((Cc + G) / (double)fn);
    out[1] = (float)(L / (double)fn);
    out[2] = fn;
  }
}

extern "C" void kernel_launch(void* const* d_in, const int* in_sizes, int n_in,
                              void* d_out, int out_size, void* d_ws, size_t ws_size,
                              hipStream_t stream) {
  const float* pred_conf = (const float*)d_in[0];
  const float* pred_loc  = (const float*)d_in[1];
  const float* anchors   = (const float*)d_in[2];
  const float* targets   = (const float*)d_in[3];
  float* out = (float*)d_out;

  char* ws = (char*)d_ws;
  int*   posCount = (int*)(ws + 0);                    // 128 B
  int*   bestA    = (int*)(ws + 128);                  // 2560 B
  float* partLoc  = (float*)(ws + 4096);               // 48 KiB
  float* partCe   = (float*)(ws + 4096 + 49152);       // 48 KiB
  float* negSumB  = (float*)(ws + 4096 + 2 * 49152);   // 128 B
  float* neg_ce   = (float*)(ws + 131072);             // B*A floats ~3.1 MiB

  hipMemsetAsync(ws, 0, 4096, stream);                 // zero posCount

  k_best_anchor<<<dim3(B_ * M_), 256, 0, stream>>>(anchors, targets, bestA);
  k_main<<<dim3(GRIDX, B_), 256, 0, stream>>>(pred_conf, pred_loc, anchors, targets,
                                              bestA, neg_ce, partLoc, partCe, posCount);
  k_select<<<dim3(B_), 256, 0, stream>>>(neg_ce, posCount, negSumB);
  k_final<<<1, 256, 0, stream>>>(posCount, partLoc, partCe, negSumB, out);
}